// Round 2
// baseline (53.609 us; speedup 1.0000x reference)
//
#include <hip/hip_runtime.h>
#include <hip/hip_cooperative_groups.h>
#include <stdint.h>

namespace cg = cooperative_groups;

typedef __attribute__((ext_vector_type(8))) short short8;   // 8 x bf16 bits
typedef __attribute__((ext_vector_type(4))) float f32x4;
typedef __attribute__((ext_vector_type(2))) float f32x2;
typedef __attribute__((ext_vector_type(2))) unsigned long long u64x2;
typedef unsigned long long u64;

// R=C=64, D=128, B=256, RC=4096.
// Single cooperative dispatch:
//  phase A: per block (bt=bid&3, nt=bid>>2) convert w[nt-tile] + x[bt-tile] -> LDS bf16
//  phase B: 64x64 dot-GEMM (mfma 16x16x32), per-wave packed argmin -> part[b][nt]
//  grid.sync()
//  phase C: per block 16 neurons: reduce 64 partials/b, gaussian gT tile,
//           T-GEMM (mfma) against xbT, fused epilogue.

static __device__ __forceinline__ unsigned short f2bf(float f) {
    uint32_t u = __float_as_uint(f);
    return (unsigned short)((u + 0x7FFFu + ((u >> 16) & 1u)) >> 16);
}

// LDS overlay:
// phase A/B: wbs[64][136] (17408 B) | xbs[64][136] (17408 B) | wn2s[64] (256 B)
// phase C  : rc[256] f32x2 (2048 B) | gT[16][264] (8448 B)   | coef[16] (64 B)
#define SMEM_BYTES (17408 + 17408 + 256)

__global__ __launch_bounds__(256) void k_som(
    const float* __restrict__ x, const float* __restrict__ w,
    const float* __restrict__ alpha_p, const float* __restrict__ sigma_p,
    float* __restrict__ out, u64* __restrict__ part,
    unsigned short* __restrict__ xbT)
{
    __shared__ __align__(16) char smem[SMEM_BYTES];
    unsigned short (*wbs)[136] = (unsigned short(*)[136])smem;
    unsigned short (*xbs)[136] = (unsigned short(*)[136])(smem + 17408);
    float* wn2s = (float*)(smem + 34816);

    const int tid = threadIdx.x;
    const int bid = blockIdx.x;
    const int bt = bid & 3, nt = bid >> 2;
    const int b0 = bt * 64, n0 = nt * 64;
    const int sub = tid & 15, rloc = tid >> 4;

    // ---------------- phase A: convert tiles into LDS ----------------
    #pragma unroll
    for (int p = 0; p < 4; ++p) {
        const int r = p * 16 + rloc;          // local row 0..63
        {   // w row (neuron n0+r) -> wbs, plus ||w||^2
            const float* src = w + (n0 + r) * 128 + sub * 8;
            f32x4 v0 = *reinterpret_cast<const f32x4*>(src);
            f32x4 v1 = *reinterpret_cast<const f32x4*>(src + 4);
            float sq = v0[0]*v0[0]+v0[1]*v0[1]+v0[2]*v0[2]+v0[3]*v0[3]
                     + v1[0]*v1[0]+v1[1]*v1[1]+v1[2]*v1[2]+v1[3]*v1[3];
            short8 pk;
            #pragma unroll
            for (int i = 0; i < 4; ++i) pk[i] = (short)f2bf(v0[i]);
            #pragma unroll
            for (int i = 0; i < 4; ++i) pk[4+i] = (short)f2bf(v1[i]);
            *reinterpret_cast<short8*>(&wbs[r][sub * 8]) = pk;
            sq += __shfl_xor(sq, 1);
            sq += __shfl_xor(sq, 2);
            sq += __shfl_xor(sq, 4);
            sq += __shfl_xor(sq, 8);
            if (sub == 0) wn2s[r] = sq;
        }
        {   // x row (batch b0+r) -> xbs
            const float* src = x + (b0 + r) * 128 + sub * 8;
            f32x4 v0 = *reinterpret_cast<const f32x4*>(src);
            f32x4 v1 = *reinterpret_cast<const f32x4*>(src + 4);
            short8 pk;
            #pragma unroll
            for (int i = 0; i < 4; ++i) pk[i] = (short)f2bf(v0[i]);
            #pragma unroll
            for (int i = 0; i < 4; ++i) pk[4+i] = (short)f2bf(v1[i]);
            *reinterpret_cast<short8*>(&xbs[r][sub * 8]) = pk;
        }
    }
    // blocks 0..15: also emit xbT [128][256] bf16 for phase C's B-operand
    if (bid < 16) {
        const int row = bid * 16 + rloc;      // batch row 0..255
        const float* src = x + row * 128 + sub * 8;
        f32x4 v0 = *reinterpret_cast<const f32x4*>(src);
        f32x4 v1 = *reinterpret_cast<const f32x4*>(src + 4);
        #pragma unroll
        for (int i = 0; i < 4; ++i) xbT[(sub*8 + i) * 256 + row] = f2bf(v0[i]);
        #pragma unroll
        for (int i = 0; i < 4; ++i) xbT[(sub*8 + 4 + i) * 256 + row] = f2bf(v1[i]);
    }
    __syncthreads();

    // ---------------- phase B: dot-GEMM + partial argmin ----------------
    {
        const int wv = tid >> 6, l = tid & 63;
        const int c = l & 15, kg = l >> 4;
        const int bw = wv * 16;               // wave's 16 batch rows (local)

        short8 a[4];
        #pragma unroll
        for (int ks = 0; ks < 4; ++ks)
            a[ks] = *reinterpret_cast<const short8*>(&xbs[bw + c][ks * 32 + kg * 8]);

        f32x4 acc[4];
        #pragma unroll
        for (int nf = 0; nf < 4; ++nf) acc[nf] = (f32x4){0.f, 0.f, 0.f, 0.f};

        #pragma unroll
        for (int ks = 0; ks < 4; ++ks) {
            #pragma unroll
            for (int nf = 0; nf < 4; ++nf) {
                short8 bfr = *reinterpret_cast<const short8*>(&wbs[nf * 16 + c][ks * 32 + kg * 8]);
                acc[nf] = __builtin_amdgcn_mfma_f32_16x16x32_bf16(a[ks], bfr, acc[nf], 0, 0, 0);
            }
        }

        float wv2[4];
        #pragma unroll
        for (int nf = 0; nf < 4; ++nf) wv2[nf] = wn2s[nf * 16 + c];

        // C/D: col = lane&15 (n), row = (lane>>4)*4 + reg (b)
        #pragma unroll
        for (int j = 0; j < 4; ++j) {
            u64 best = 0xFFFFFFFFFFFFFFFFull;
            #pragma unroll
            for (int nf = 0; nf < 4; ++nf) {
                float keyf = 0.5f * wv2[nf] - acc[nf][j];
                uint32_t u = __float_as_uint(keyf);
                u = ((int)u >= 0) ? (u | 0x80000000u) : ~u;   // monotone map
                u64 pk = ((u64)u << 32) | (u64)(n0 + nf * 16 + c);
                best = (pk < best) ? pk : best;
            }
            #pragma unroll
            for (int m = 1; m < 16; m <<= 1) {
                u64 o = __shfl_xor(best, m);
                best = (o < best) ? o : best;
            }
            if (c == 0)
                part[(u64)(b0 + bw + kg * 4 + j) * 64 + nt] = best;
        }
    }

    cg::this_grid().sync();

    // ---------------- phase C: neighborhood update ----------------
    f32x2* rc = (f32x2*)smem;
    unsigned short (*gT)[264] = (unsigned short(*)[264])(smem + 2048);
    float* coef = (float*)(smem + 2048 + 8448);

    const int n0c = bid * 16;
    const float alpha = alpha_p[0], sigma = sigma_p[0];
    const float inv_s2 = 1.0f / (sigma * sigma);
    const float aB = alpha * (1.0f / 256.0f);

    {   // per-thread BMU reduce for batch b = tid (64 partials)
        const u64x2* pp = (const u64x2*)(part + (u64)tid * 64);
        u64 best = 0xFFFFFFFFFFFFFFFFull;
        #pragma unroll
        for (int i = 0; i < 32; ++i) {
            u64x2 v = pp[i];
            u64 m = (v[0] < v[1]) ? v[0] : v[1];
            best = (m < best) ? m : best;
        }
        int idx = (int)(uint32_t)(best & 0xFFFFFFFFull);
        f32x2 rcv;
        rcv[0] = (float)(idx >> 6);
        rcv[1] = (float)(idx & 63);
        rc[tid] = rcv;
    }
    __syncthreads();

    {   // gaussian neighborhood tile gT[16 n][256 b] + coef
        const int nl = tid >> 4, bq = tid & 15;
        const int n = n0c + nl;
        const float nr = (float)(n >> 6), nc = (float)(n & 63);
        float s = 0.f;
        #pragma unroll
        for (int j = 0; j < 16; ++j) {
            const int b = bq + 16 * j;
            f32x2 rcv = rc[b];
            float dr = rcv[0] - nr, dc = rcv[1] - nc;
            float g = __expf(-(dr * dr + dc * dc) * inv_s2);
            s += g;
            gT[nl][b] = f2bf(g);
        }
        s += __shfl_xor(s, 1);
        s += __shfl_xor(s, 2);
        s += __shfl_xor(s, 4);
        s += __shfl_xor(s, 8);
        if (bq == 0) coef[nl] = 1.0f - aB * s;
    }
    __syncthreads();

    {   // T[n][d] = sum_b gT[n][b] * x[b][d] via MFMA; fused epilogue
        const int wv = tid >> 6, l = tid & 63;
        const int c = l & 15, kg = l >> 4;
        f32x4 acc[2];
        acc[0] = (f32x4){0.f, 0.f, 0.f, 0.f};
        acc[1] = (f32x4){0.f, 0.f, 0.f, 0.f};

        #pragma unroll
        for (int ks = 0; ks < 8; ++ks) {
            short8 a = *reinterpret_cast<const short8*>(&gT[c][ks * 32 + kg * 8]);
            #pragma unroll
            for (int nf = 0; nf < 2; ++nf) {
                const int d = wv * 32 + nf * 16 + c;
                short8 bfr = *reinterpret_cast<const short8*>(xbT + d * 256 + ks * 32 + kg * 8);
                acc[nf] = __builtin_amdgcn_mfma_f32_16x16x32_bf16(a, bfr, acc[nf], 0, 0, 0);
            }
        }

        #pragma unroll
        for (int nf = 0; nf < 2; ++nf) {
            #pragma unroll
            for (int j = 0; j < 4; ++j) {
                const int nloc = kg * 4 + j;
                const int d = wv * 32 + nf * 16 + c;
                const int gi = (n0c + nloc) * 128 + d;
                out[gi] = w[gi] * coef[nloc] + aB * acc[nf][j];
            }
        }
    }
}

// ---------------------------------------------------------------------------
extern "C" void kernel_launch(void* const* d_in, const int* in_sizes, int n_in,
                              void* d_out, int out_size, void* d_ws, size_t ws_size,
                              hipStream_t stream) {
    const float* x     = (const float*)d_in[0];   // [256][128]
    const float* w     = (const float*)d_in[1];   // [64][64][128]
    const float* alpha = (const float*)d_in[2];
    const float* sigma = (const float*)d_in[3];
    float* out = (float*)d_out;

    char* ws = (char*)d_ws;
    u64*            part = (u64*)ws;                         // 256*64*8 = 131072 B
    unsigned short* xbT  = (unsigned short*)(ws + 131072);   // 128*256*2 = 65536 B

    void* args[] = { (void*)&x, (void*)&w, (void*)&alpha, (void*)&sigma,
                     (void*)&out, (void*)&part, (void*)&xbT };
    hipLaunchCooperativeKernel((const void*)k_som, dim3(256), dim3(256),
                               args, 0, stream);
}

// Round 3
// 20.158 us; speedup vs baseline: 2.6595x; 2.6595x over previous
//
#include <hip/hip_runtime.h>
#include <stdint.h>

typedef __attribute__((ext_vector_type(8))) short short8;   // 8 x bf16 bits
typedef __attribute__((ext_vector_type(4))) float f32x4;
typedef __attribute__((ext_vector_type(2))) float f32x2;
typedef __attribute__((ext_vector_type(2))) unsigned long long u64x2;
typedef unsigned long long u64;

// R=C=64, D=128, B=256, RC=4096.
// Two plain dispatches (no coop launch, no atomics, no memset):
//  K1: per block (bt=bid&3, nt=bid>>2): convert w[nt]/x[bt] tiles -> LDS bf16,
//      64x64 dot-GEMM (mfma 16x16x32), per-wave packed argmin -> part[b][nt].
//      Blocks 0..15 also emit xbT [128][256] bf16.
//  K2: per block (16 neurons): reduce 64 partials per b -> BMU coords,
//      gaussian gT tile + S[n], MFMA T-GEMM vs xbT, fused epilogue.

static __device__ __forceinline__ unsigned short f2bf(float f) {
    uint32_t u = __float_as_uint(f);
    return (unsigned short)((u + 0x7FFFu + ((u >> 16) & 1u)) >> 16);
}

__global__ __launch_bounds__(256) void k_bmu(
    const float* __restrict__ x, const float* __restrict__ w,
    u64* __restrict__ part, unsigned short* __restrict__ xbT)
{
    // wbs[64][136] | xbs[64][136] | wn2s[64]  (~35 KB)
    __shared__ __align__(16) unsigned short wbs[64][136];
    __shared__ __align__(16) unsigned short xbs[64][136];
    __shared__ float wn2s[64];

    const int tid = threadIdx.x;
    const int bid = blockIdx.x;
    const int bt = bid & 3, nt = bid >> 2;
    const int b0 = bt * 64, n0 = nt * 64;
    const int sub = tid & 15, rloc = tid >> 4;

    // ---- phase A: convert tiles into LDS ----
    #pragma unroll
    for (int p = 0; p < 4; ++p) {
        const int r = p * 16 + rloc;          // local row 0..63
        {   // w row (neuron n0+r) -> wbs, plus ||w||^2
            const float* src = w + (n0 + r) * 128 + sub * 8;
            f32x4 v0 = *reinterpret_cast<const f32x4*>(src);
            f32x4 v1 = *reinterpret_cast<const f32x4*>(src + 4);
            float sq = v0[0]*v0[0]+v0[1]*v0[1]+v0[2]*v0[2]+v0[3]*v0[3]
                     + v1[0]*v1[0]+v1[1]*v1[1]+v1[2]*v1[2]+v1[3]*v1[3];
            short8 pk;
            #pragma unroll
            for (int i = 0; i < 4; ++i) pk[i] = (short)f2bf(v0[i]);
            #pragma unroll
            for (int i = 0; i < 4; ++i) pk[4+i] = (short)f2bf(v1[i]);
            *reinterpret_cast<short8*>(&wbs[r][sub * 8]) = pk;
            sq += __shfl_xor(sq, 1);
            sq += __shfl_xor(sq, 2);
            sq += __shfl_xor(sq, 4);
            sq += __shfl_xor(sq, 8);
            if (sub == 0) wn2s[r] = sq;
        }
        {   // x row (batch b0+r) -> xbs
            const float* src = x + (b0 + r) * 128 + sub * 8;
            f32x4 v0 = *reinterpret_cast<const f32x4*>(src);
            f32x4 v1 = *reinterpret_cast<const f32x4*>(src + 4);
            short8 pk;
            #pragma unroll
            for (int i = 0; i < 4; ++i) pk[i] = (short)f2bf(v0[i]);
            #pragma unroll
            for (int i = 0; i < 4; ++i) pk[4+i] = (short)f2bf(v1[i]);
            *reinterpret_cast<short8*>(&xbs[r][sub * 8]) = pk;
        }
    }
    // blocks 0..15: emit xbT [128][256] bf16 for K2's B-operand
    if (bid < 16) {
        const int row = bid * 16 + rloc;      // batch row 0..255
        const float* src = x + row * 128 + sub * 8;
        f32x4 v0 = *reinterpret_cast<const f32x4*>(src);
        f32x4 v1 = *reinterpret_cast<const f32x4*>(src + 4);
        #pragma unroll
        for (int i = 0; i < 4; ++i) xbT[(sub*8 + i) * 256 + row] = f2bf(v0[i]);
        #pragma unroll
        for (int i = 0; i < 4; ++i) xbT[(sub*8 + 4 + i) * 256 + row] = f2bf(v1[i]);
    }
    __syncthreads();

    // ---- phase B: dot-GEMM + per-wave packed argmin ----
    const int wv = tid >> 6, l = tid & 63;
    const int c = l & 15, kg = l >> 4;
    const int bw = wv * 16;                   // wave's 16 batch rows (local)

    short8 a[4];
    #pragma unroll
    for (int ks = 0; ks < 4; ++ks)
        a[ks] = *reinterpret_cast<const short8*>(&xbs[bw + c][ks * 32 + kg * 8]);

    f32x4 acc[4];
    #pragma unroll
    for (int nf = 0; nf < 4; ++nf) acc[nf] = (f32x4){0.f, 0.f, 0.f, 0.f};

    #pragma unroll
    for (int ks = 0; ks < 4; ++ks) {
        #pragma unroll
        for (int nf = 0; nf < 4; ++nf) {
            short8 bfr = *reinterpret_cast<const short8*>(&wbs[nf * 16 + c][ks * 32 + kg * 8]);
            acc[nf] = __builtin_amdgcn_mfma_f32_16x16x32_bf16(a[ks], bfr, acc[nf], 0, 0, 0);
        }
    }

    float wv2[4];
    #pragma unroll
    for (int nf = 0; nf < 4; ++nf) wv2[nf] = wn2s[nf * 16 + c];

    // C/D: col = lane&15 (n), row = (lane>>4)*4 + reg (b)
    #pragma unroll
    for (int j = 0; j < 4; ++j) {
        u64 best = 0xFFFFFFFFFFFFFFFFull;
        #pragma unroll
        for (int nf = 0; nf < 4; ++nf) {
            float keyf = 0.5f * wv2[nf] - acc[nf][j];
            uint32_t u = __float_as_uint(keyf);
            u = ((int)u >= 0) ? (u | 0x80000000u) : ~u;   // monotone map
            u64 pk = ((u64)u << 32) | (u64)(n0 + nf * 16 + c);
            best = (pk < best) ? pk : best;
        }
        #pragma unroll
        for (int m = 1; m < 16; m <<= 1) {
            u64 o = __shfl_xor(best, m);
            best = (o < best) ? o : best;
        }
        if (c == 0)
            part[(u64)(b0 + bw + kg * 4 + j) * 64 + nt] = best;
    }
}

__global__ __launch_bounds__(256) void k_update(
    const unsigned short* __restrict__ xbT, const float* __restrict__ w,
    const u64* __restrict__ part, const float* __restrict__ alpha_p,
    const float* __restrict__ sigma_p, float* __restrict__ out)
{
    __shared__ f32x2 rc[256];
    __shared__ unsigned short gT[16][264];   // +8 pad: 2-way bank aliasing (free)
    __shared__ float coef[16];

    const int tid = threadIdx.x;
    const int n0 = blockIdx.x * 16;
    const float alpha = alpha_p[0], sigma = sigma_p[0];
    const float inv_s2 = 1.0f / (sigma * sigma);
    const float aB = alpha * (1.0f / 256.0f);

    {   // per-thread BMU reduce for batch b = tid (64 partials, vectorized)
        const u64x2* pp = (const u64x2*)(part + (u64)tid * 64);
        u64 best = 0xFFFFFFFFFFFFFFFFull;
        #pragma unroll
        for (int i = 0; i < 32; ++i) {
            u64x2 v = pp[i];
            u64 m = (v[0] < v[1]) ? v[0] : v[1];
            best = (m < best) ? m : best;
        }
        int idx = (int)(uint32_t)(best & 0xFFFFFFFFull);
        f32x2 rcv;
        rcv[0] = (float)(idx >> 6);
        rcv[1] = (float)(idx & 63);
        rc[tid] = rcv;
    }
    __syncthreads();

    {   // gaussian neighborhood tile gT[16 n][256 b] + coef
        const int nl = tid >> 4, bq = tid & 15;
        const int n = n0 + nl;
        const float nr = (float)(n >> 6), nc = (float)(n & 63);
        float s = 0.f;
        #pragma unroll
        for (int j = 0; j < 16; ++j) {
            const int b = bq + 16 * j;
            f32x2 rcv = rc[b];
            float dr = rcv[0] - nr, dc = rcv[1] - nc;
            float g = __expf(-(dr * dr + dc * dc) * inv_s2);
            s += g;
            gT[nl][b] = f2bf(g);
        }
        s += __shfl_xor(s, 1);
        s += __shfl_xor(s, 2);
        s += __shfl_xor(s, 4);
        s += __shfl_xor(s, 8);
        if (bq == 0) coef[nl] = 1.0f - aB * s;
    }
    __syncthreads();

    {   // T[n][d] = sum_b gT[n][b] * x[b][d] via MFMA; fused epilogue
        const int wv = tid >> 6, l = tid & 63;
        const int c = l & 15, kg = l >> 4;
        f32x4 acc[2];
        acc[0] = (f32x4){0.f, 0.f, 0.f, 0.f};
        acc[1] = (f32x4){0.f, 0.f, 0.f, 0.f};

        #pragma unroll
        for (int ks = 0; ks < 8; ++ks) {
            short8 a = *reinterpret_cast<const short8*>(&gT[c][ks * 32 + kg * 8]);
            #pragma unroll
            for (int nf = 0; nf < 2; ++nf) {
                const int d = wv * 32 + nf * 16 + c;
                short8 bfr = *reinterpret_cast<const short8*>(xbT + d * 256 + ks * 32 + kg * 8);
                acc[nf] = __builtin_amdgcn_mfma_f32_16x16x32_bf16(a, bfr, acc[nf], 0, 0, 0);
            }
        }

        #pragma unroll
        for (int nf = 0; nf < 2; ++nf) {
            #pragma unroll
            for (int j = 0; j < 4; ++j) {
                const int nloc = kg * 4 + j;
                const int d = wv * 32 + nf * 16 + c;
                const int gi = (n0 + nloc) * 128 + d;
                out[gi] = w[gi] * coef[nloc] + aB * acc[nf][j];
            }
        }
    }
}

// ---------------------------------------------------------------------------
extern "C" void kernel_launch(void* const* d_in, const int* in_sizes, int n_in,
                              void* d_out, int out_size, void* d_ws, size_t ws_size,
                              hipStream_t stream) {
    const float* x     = (const float*)d_in[0];   // [256][128]
    const float* w     = (const float*)d_in[1];   // [64][64][128]
    const float* alpha = (const float*)d_in[2];
    const float* sigma = (const float*)d_in[3];
    float* out = (float*)d_out;

    char* ws = (char*)d_ws;
    u64*            part = (u64*)ws;                         // 256*64*8 = 131072 B
    unsigned short* xbT  = (unsigned short*)(ws + 131072);   // 128*256*2 = 65536 B

    k_bmu<<<256, 256, 0, stream>>>(x, w, part, xbT);
    k_update<<<256, 256, 0, stream>>>(xbT, w, part, alpha, sigma, out);
}